// Round 1
// baseline (335.425 us; speedup 1.0000x reference)
//
#include <hip/hip_runtime.h>
#include <stdint.h>

typedef __bf16 bf16x8 __attribute__((ext_vector_type(8)));
typedef float f32x4 __attribute__((ext_vector_type(4)));
typedef int i32x4 __attribute__((ext_vector_type(4)));
typedef unsigned short u16;

#define DEVI static __device__ __forceinline__

// f32 -> bf16 (RNE) without hip_bf16 dependency
DEVI u16 bfu(float f){
  unsigned u = __builtin_bit_cast(unsigned, f);
  unsigned r = u + 0x7fffu + ((u >> 16) & 1u);
  return (u16)(r >> 16);
}
DEVI unsigned packbf(float a, float b){
  return (unsigned)bfu(a) | ((unsigned)bfu(b) << 16);
}

// 256-thread block max-reduce
DEVI float blockReduceMax(float v, float* sred){
  for (int off = 32; off; off >>= 1) v = fmaxf(v, __shfl_xor(v, off));
  int w = threadIdx.x >> 6;
  if ((threadIdx.x & 63) == 0) sred[w] = v;
  __syncthreads();
  float r = fmaxf(fmaxf(sred[0], sred[1]), fmaxf(sred[2], sred[3]));
  __syncthreads();
  return r;
}

// ---------------- quantize kernels ----------------
// rows of length 1024: amax -> scale, int8 quant, bf16 copy
__global__ void quant_rows(const float* __restrict__ in, int8_t* __restrict__ qo,
                           u16* __restrict__ bo, float* __restrict__ so){
  __shared__ float sred[4];
  const int row = blockIdx.x, t = threadIdx.x;
  const float4 v = *(const float4*)(in + (size_t)row * 1024 + t * 4);
  float am = fmaxf(fmaxf(fabsf(v.x), fabsf(v.y)), fmaxf(fabsf(v.z), fabsf(v.w)));
  am = blockReduceMax(am, sred);
  const float s = fmaxf(am, 1e-5f) / 127.0f;
  if (t == 0) so[row] = s;
  char4 q;
  q.x = (int8_t)(int)fminf(fmaxf(rintf(v.x / s), -128.f), 127.f);
  q.y = (int8_t)(int)fminf(fmaxf(rintf(v.y / s), -128.f), 127.f);
  q.z = (int8_t)(int)fminf(fmaxf(rintf(v.z / s), -128.f), 127.f);
  q.w = (int8_t)(int)fminf(fmaxf(rintf(v.w / s), -128.f), 127.f);
  *(char4*)(qo + (size_t)row * 1024 + t * 4) = q;
  ushort4 h; h.x = bfu(v.x); h.y = bfu(v.y); h.z = bfu(v.z); h.w = bfu(v.w);
  *(ushort4*)(bo + (size_t)row * 1024 + t * 4) = h;
}

// b_qkv: single scale over 3072, store dequantized values
__global__ void quant_b(const float* __restrict__ b, float* __restrict__ qb){
  __shared__ float sred[4];
  const int t = threadIdx.x;
  float am = 0.f;
  for (int i = t; i < 3072; i += 256) am = fmaxf(am, fabsf(b[i]));
  am = blockReduceMax(am, sred);
  const float s = fmaxf(am, 1e-5f) / 127.0f;
  for (int i = t; i < 3072; i += 256){
    float q = fminf(fmaxf(rintf(b[i] / s), -128.f), 127.f);
    qb[i] = q * s;
  }
}

__global__ void f32_to_bf16(const float* __restrict__ in, u16* __restrict__ out){
  const int i = (blockIdx.x * 256 + threadIdx.x) * 4;
  float4 v = *(const float4*)(in + i);
  ushort4 h; h.x = bfu(v.x); h.y = bfu(v.y); h.z = bfu(v.z); h.w = bfu(v.w);
  *(ushort4*)(out + i) = h;
}

// ---------------- int8 GEMM: q_lin = sx*sw*(ix.iw^T) + qb ----------------
// M=4096, N=3072, K=1024
__global__ __launch_bounds__(256) void gemm_i8(const int8_t* __restrict__ A, const int8_t* __restrict__ Bm,
    const float* __restrict__ sx, const float* __restrict__ sw, const float* __restrict__ qb,
    float* __restrict__ out){
  __shared__ int8_t As[128 * 64];
  __shared__ int8_t Bs[128 * 64];
  const int t = threadIdx.x, l = t & 63, w = t >> 6;
  const int m0 = blockIdx.y * 128, n0 = blockIdx.x * 128;
  const int wm = (w >> 1) * 64, wn = (w & 1) * 64, lr = l & 15, lg = l >> 4;
  i32x4 acc[4][4];
  i32x4 z = {0, 0, 0, 0};
  for (int i = 0; i < 4; i++) for (int j = 0; j < 4; j++) acc[i][j] = z;
  for (int kt = 0; kt < 16; kt++){
    __syncthreads();
    for (int it = 0; it < 2; it++){
      int c = t + it * 256, r = c >> 2, off = (c & 3) * 16;
      *(uint4*)(&As[c * 16]) = *(const uint4*)(A + (size_t)(m0 + r) * 1024 + kt * 64 + off);
      *(uint4*)(&Bs[c * 16]) = *(const uint4*)(Bm + (size_t)(n0 + r) * 1024 + kt * 64 + off);
    }
    __syncthreads();
    i32x4 a[4], b[4];
    for (int i = 0; i < 4; i++) a[i] = *(const i32x4*)(&As[(wm + i * 16 + lr) * 64 + lg * 16]);
    for (int j = 0; j < 4; j++) b[j] = *(const i32x4*)(&Bs[(wn + j * 16 + lr) * 64 + lg * 16]);
    for (int i = 0; i < 4; i++)
      for (int j = 0; j < 4; j++)
        acc[i][j] = __builtin_amdgcn_mfma_i32_16x16x64_i8(a[i], b[j], acc[i][j], 0, 0, 0);
  }
  for (int i = 0; i < 4; i++){
    int row = m0 + wm + i * 16 + lg * 4;
    for (int j = 0; j < 4; j++){
      int col = n0 + wn + j * 16 + lr;
      float swc = sw[col], qbc = qb[col];
      for (int r = 0; r < 4; r++)
        out[(size_t)(row + r) * 3072 + col] = (float)acc[i][j][r] * sx[row + r] * swc + qbc;
    }
  }
}

// ---------------- q_lin row quantize -> s_ql, iq, ik ----------------
__global__ void qlin_quant(const float* __restrict__ qlin, float* __restrict__ s_ql,
                           int8_t* __restrict__ iq, int8_t* __restrict__ ik){
  __shared__ float sred[4];
  const int row = blockIdx.x, t = threadIdx.x;
  const float* rp = qlin + (size_t)row * 3072;
  float am = 0.f;
  for (int i = 0; i < 3; i++){
    float4 v = *(const float4*)(rp + t * 4 + i * 1024);
    am = fmaxf(am, fmaxf(fmaxf(fabsf(v.x), fabsf(v.y)), fmaxf(fabsf(v.z), fabsf(v.w))));
  }
  am = blockReduceMax(am, sred);
  const float s = fmaxf(am, 1e-5f) / 127.0f;
  if (t == 0) s_ql[row] = s;
  const int b_ = row >> 10, n = row & 1023;
  const int o0 = t * 8;                     // 0..2047
  int8_t* dst = (o0 < 1024) ? iq : ik;
  const int oo = o0 & 1023, h = oo >> 6, d = oo & 63;
  const size_t base = (((size_t)(b_ * 16 + h) * 1024 + n) * 64 + d);
  union { int8_t c[8]; unsigned long long u; } pk;
  for (int j = 0; j < 8; j++)
    pk.c[j] = (int8_t)(int)fminf(fmaxf(rintf(rp[o0 + j] / s), -128.f), 127.f);
  *(unsigned long long*)(dst + base) = pk.u;
}

// ---------------- bf16 GEMM (MODE 0: QKV scatter+bias, MODE 1: proj f32 out) ----------------
template<int MODE>
__global__ __launch_bounds__(256) void gemm_bf16(const u16* __restrict__ A, const u16* __restrict__ Bm,
    const float* __restrict__ bias, void* __restrict__ outp, int K, int N){
  __shared__ u16 As[128 * 32];
  __shared__ u16 Bs[128 * 32];
  const int t = threadIdx.x, l = t & 63, w = t >> 6;
  const int m0 = blockIdx.y * 128, n0 = blockIdx.x * 128;
  const int wm = (w >> 1) * 64, wn = (w & 1) * 64, lr = l & 15, lg = l >> 4;
  f32x4 acc[4][4];
  f32x4 z = {0.f, 0.f, 0.f, 0.f};
  for (int i = 0; i < 4; i++) for (int j = 0; j < 4; j++) acc[i][j] = z;
  const int nkt = K >> 5;
  for (int kt = 0; kt < nkt; kt++){
    __syncthreads();
    for (int it = 0; it < 2; it++){
      int c = t + it * 256, r = c >> 2, off = (c & 3) * 8;
      *(uint4*)(&As[c * 8]) = *(const uint4*)(A + (size_t)(m0 + r) * K + kt * 32 + off);
      *(uint4*)(&Bs[c * 8]) = *(const uint4*)(Bm + (size_t)(n0 + r) * K + kt * 32 + off);
    }
    __syncthreads();
    bf16x8 a[4], b[4];
    for (int i = 0; i < 4; i++) a[i] = *(const bf16x8*)(&As[(wm + i * 16 + lr) * 32 + lg * 8]);
    for (int j = 0; j < 4; j++) b[j] = *(const bf16x8*)(&Bs[(wn + j * 16 + lr) * 32 + lg * 8]);
    for (int i = 0; i < 4; i++)
      for (int j = 0; j < 4; j++)
        acc[i][j] = __builtin_amdgcn_mfma_f32_16x16x32_bf16(a[i], b[j], acc[i][j], 0, 0, 0);
  }
  for (int i = 0; i < 4; i++){
    int row = m0 + wm + i * 16 + lg * 4;
    for (int j = 0; j < 4; j++){
      int col = n0 + wn + j * 16 + lr;
      float bc = bias[col];
      for (int r = 0; r < 4; r++){
        float v = acc[i][j][r] + bc;
        if (MODE == 0){
          int s = col >> 10, h = (col >> 6) & 15, d = col & 63;
          int b_ = (row + r) >> 10, n = (row + r) & 1023;
          ((u16*)outp)[(((size_t)(s * 64 + b_ * 16 + h)) * 1024 + n) * 64 + d] = bfu(v);
        } else {
          ((float*)outp)[(size_t)(row + r) * N + col] = v;
        }
      }
    }
  }
}

// ---------------- flash attention, 4 waves x 16 q-rows, swapped S^T scheme ----------------
__global__ __launch_bounds__(256) void attn(const u16* __restrict__ qkv, u16* __restrict__ aout){
  __shared__ u16 Ks[32 * 64];
  __shared__ u16 Vt[64 * 32];
  const int t = threadIdx.x, l = t & 63, w = t >> 6, lr = l & 15, lg = l >> 4;
  const int bz = blockIdx.y, qt = blockIdx.x;
  const int b_ = bz >> 4, h = bz & 15;
  const u16* Q  = qkv + (size_t)bz * 65536;
  const u16* Kg = qkv + (size_t)(64 + bz) * 65536;
  const u16* Vg = qkv + (size_t)(128 + bz) * 65536;
  const int q0 = qt * 64 + w * 16;
  const bf16x8 bq0 = *(const bf16x8*)(Q + (size_t)(q0 + lr) * 64 + lg * 8);
  const bf16x8 bq1 = *(const bf16x8*)(Q + (size_t)(q0 + lr) * 64 + 32 + lg * 8);
  float m = -1e30f, lsum = 0.f;
  f32x4 o[4];
  f32x4 zf = {0.f, 0.f, 0.f, 0.f};
  for (int dt = 0; dt < 4; dt++) o[dt] = zf;
  const int hi = lg & 1, tt = lg >> 1;
  const int srcA = lr + 32 * hi, srcB = srcA + 16;
  for (int kv0 = 0; kv0 < 1024; kv0 += 32){
    __syncthreads();
    {
      int r = t >> 3, off = (t & 7) * 8;
      *(uint4*)(&Ks[t * 8]) = *(const uint4*)(Kg + (size_t)(kv0 + r) * 64 + off);
      uint4 vv = *(const uint4*)(Vg + (size_t)(kv0 + r) * 64 + off);
      const u16* pv = (const u16*)&vv;
      for (int j = 0; j < 8; j++) Vt[(off + j) * 32 + r] = pv[j];
    }
    __syncthreads();
    f32x4 st[2];
    for (int kvt = 0; kvt < 2; kvt++){
      bf16x8 ak0 = *(const bf16x8*)(&Ks[(kvt * 16 + lr) * 64 + lg * 8]);
      bf16x8 ak1 = *(const bf16x8*)(&Ks[(kvt * 16 + lr) * 64 + 32 + lg * 8]);
      f32x4 c = zf;
      c = __builtin_amdgcn_mfma_f32_16x16x32_bf16(ak0, bq0, c, 0, 0, 0);
      c = __builtin_amdgcn_mfma_f32_16x16x32_bf16(ak1, bq1, c, 0, 0, 0);
      st[kvt] = c;
    }
    float tmax = -1e30f;
    for (int kvt = 0; kvt < 2; kvt++)
      for (int r = 0; r < 4; r++){ st[kvt][r] *= 0.125f; tmax = fmaxf(tmax, st[kvt][r]); }
    tmax = fmaxf(tmax, __shfl_xor(tmax, 16));
    tmax = fmaxf(tmax, __shfl_xor(tmax, 32));
    const float mn = fmaxf(m, tmax);
    const float f = __expf(m - mn);
    m = mn;
    float p[2][4], psum = 0.f;
    for (int kvt = 0; kvt < 2; kvt++)
      for (int r = 0; r < 4; r++){ float e = __expf(st[kvt][r] - mn); p[kvt][r] = e; psum += e; }
    psum += __shfl_xor(psum, 16);
    psum += __shfl_xor(psum, 32);
    lsum = lsum * f + psum;
    for (int dt = 0; dt < 4; dt++) for (int r = 0; r < 4; r++) o[dt][r] *= f;
    // repack P^T (C-layout) -> B-frag layout via shuffles
    int pk00 = (int)packbf(p[0][0], p[0][1]), pk01 = (int)packbf(p[0][2], p[0][3]);
    int pk10 = (int)packbf(p[1][0], p[1][1]), pk11 = (int)packbf(p[1][2], p[1][3]);
    int a0 = __shfl(pk00, srcA), a1 = __shfl(pk10, srcA);
    int b0 = __shfl(pk01, srcA), b1 = __shfl(pk11, srcA);
    int c0 = __shfl(pk00, srcB), c1 = __shfl(pk10, srcB);
    int d0 = __shfl(pk01, srcB), d1 = __shfl(pk11, srcB);
    union { unsigned u[4]; bf16x8 v; } bp;
    bp.u[0] = (unsigned)(tt ? a1 : a0);
    bp.u[1] = (unsigned)(tt ? b1 : b0);
    bp.u[2] = (unsigned)(tt ? c1 : c0);
    bp.u[3] = (unsigned)(tt ? d1 : d0);
    for (int dt = 0; dt < 4; dt++){
      bf16x8 av = *(const bf16x8*)(&Vt[(dt * 16 + lr) * 32 + lg * 8]);
      o[dt] = __builtin_amdgcn_mfma_f32_16x16x32_bf16(av, bp.v, o[dt], 0, 0, 0);
    }
  }
  const float rn = 1.0f / lsum;
  for (int dt = 0; dt < 4; dt++){
    ushort4 hv;
    hv.x = bfu(o[dt][0] * rn); hv.y = bfu(o[dt][1] * rn);
    hv.z = bfu(o[dt][2] * rn); hv.w = bfu(o[dt][3] * rn);
    *(ushort4*)(aout + ((size_t)(b_ * 1024 + q0 + lr)) * 1024 + h * 64 + dt * 16 + lg * 4) = hv;
  }
}

// ---------------- q_attn: exact int8 scores ----------------
__global__ __launch_bounds__(256) void qattn(const int8_t* __restrict__ iq, const int8_t* __restrict__ ik,
    const float* __restrict__ s_ql, float* __restrict__ outp){
  const int t = threadIdx.x, l = t & 63, w = t >> 6, lr = l & 15, lg = l >> 4;
  const int bz = blockIdx.z, m0 = blockIdx.y * 128, n0 = blockIdx.x * 128;
  const int wm = (w >> 1) * 64, wn = (w & 1) * 64;
  const int b_ = bz >> 4;
  const int8_t* Aq = iq + (size_t)bz * 65536;
  const int8_t* Bk = ik + (size_t)bz * 65536;
  i32x4 a[4], b[4];
  for (int i = 0; i < 4; i++) a[i] = *(const i32x4*)(Aq + (size_t)(m0 + wm + i * 16 + lr) * 64 + lg * 16);
  for (int j = 0; j < 4; j++) b[j] = *(const i32x4*)(Bk + (size_t)(n0 + wn + j * 16 + lr) * 64 + lg * 16);
  float* op = outp + 4194304 + (size_t)bz * 1048576;
  i32x4 z = {0, 0, 0, 0};
  for (int i = 0; i < 4; i++){
    int row = m0 + wm + i * 16 + lg * 4;
    for (int j = 0; j < 4; j++){
      i32x4 acc = __builtin_amdgcn_mfma_i32_16x16x64_i8(a[i], b[j], z, 0, 0, 0);
      int col = n0 + wn + j * 16 + lr;
      float sc = s_ql[b_ * 1024 + col] * 0.125f;
      for (int r = 0; r < 4; r++)
        op[(size_t)(row + r) * 1024 + col] = (float)acc[r] * s_ql[b_ * 1024 + row + r] * sc;
    }
  }
}

// ---------------- topk path (tiny, f32 exact) ----------------
__global__ void topk_lin(const float* __restrict__ x, const float* __restrict__ Wq,
                         const float* __restrict__ bq, float* __restrict__ tlin){
  const int idx = blockIdx.x * 256 + threadIdx.x;  // 4*17*2048 = 139264
  const int o = idx & 2047, bn = idx >> 11;
  const int b_ = bn / 17, n = bn % 17;
  const float* xr = x + ((size_t)b_ * 1024 + n) * 1024;
  const float* wr = Wq + (size_t)o * 1024;
  float s = 0.f;
  for (int c = 0; c < 257; c++) s += xr[c] * wr[c];
  tlin[idx] = s + bq[o];
}

__global__ void topk_attn_k(const float* __restrict__ tlin, float* __restrict__ outp){
  const int idx = blockIdx.x * 256 + threadIdx.x;
  if (idx >= 4 * 16 * 17 * 17) return;
  const int mm = idx % 17; int rest = idx / 17;
  const int nn = rest % 17; rest /= 17;
  const int h = rest % 16; const int b_ = rest / 16;
  const float* tq = tlin + ((size_t)(b_ * 17 + nn)) * 2048 + h * 64;
  const float* tk = tlin + ((size_t)(b_ * 17 + mm)) * 2048 + 1024 + h * 64;
  float s = 0.f;
  for (int d = 0; d < 64; d++) s += tq[d] * tk[d];
  outp[71303168 + idx] = s * 0.125f;
}

// ---------------- launcher ----------------
extern "C" void kernel_launch(void* const* d_in, const int* in_sizes, int n_in,
                              void* d_out, int out_size, void* d_ws, size_t ws_size,
                              hipStream_t stream){
  const float* x  = (const float*)d_in[0];
  const float* Wq = (const float*)d_in[1];
  const float* bq = (const float*)d_in[2];
  const float* Wp = (const float*)d_in[3];
  const float* bp = (const float*)d_in[4];
  char* ws = (char*)d_ws;
  size_t off = 0;
  auto alloc = [&](size_t bytes) -> void* {
    void* p = ws + off; off += (bytes + 255) & ~(size_t)255; return p;
  };
  float*  qlin = (float*) alloc(4096ull * 3072 * 4);   // 48 MB
  int8_t* ix   = (int8_t*)alloc(4096ull * 1024);
  int8_t* iw   = (int8_t*)alloc(3072ull * 1024);
  int8_t* iq   = (int8_t*)alloc(64ull * 1024 * 64);
  int8_t* ik   = (int8_t*)alloc(64ull * 1024 * 64);
  u16*    xb   = (u16*)   alloc(4096ull * 1024 * 2);
  u16*    Wb   = (u16*)   alloc(3072ull * 1024 * 2);
  u16*    qkv  = (u16*)   alloc(3ull * 64 * 1024 * 64 * 2);
  u16*    aout = (u16*)   alloc(4096ull * 1024 * 2);
  u16*    Wpb  = (u16*)   alloc(1024ull * 1024 * 2);
  float*  tlin = (float*) alloc(4ull * 17 * 2048 * 4);
  float*  sx   = (float*) alloc(4096 * 4);
  float*  sw   = (float*) alloc(3072 * 4);
  float*  qbv  = (float*) alloc(3072 * 4);
  float*  sql  = (float*) alloc(4096 * 4);
  float*  dout = (float*)d_out;

  quant_rows<<<4096, 256, 0, stream>>>(x, ix, xb, sx);
  quant_rows<<<3072, 256, 0, stream>>>(Wq, iw, Wb, sw);
  quant_b<<<1, 256, 0, stream>>>(bq, qbv);
  f32_to_bf16<<<1024, 256, 0, stream>>>(Wp, Wpb);
  gemm_i8<<<dim3(24, 32), 256, 0, stream>>>(ix, iw, sx, sw, qbv, qlin);
  qlin_quant<<<4096, 256, 0, stream>>>(qlin, sql, iq, ik);
  gemm_bf16<0><<<dim3(24, 32), 256, 0, stream>>>(xb, Wb, bq, qkv, 1024, 3072);
  attn<<<dim3(16, 64), 256, 0, stream>>>(qkv, aout);
  gemm_bf16<1><<<dim3(8, 32), 256, 0, stream>>>(aout, Wpb, bp, dout, 1024, 1024);
  qattn<<<dim3(8, 8, 64), 256, 0, stream>>>(iq, ik, sql, dout);
  topk_lin<<<544, 256, 0, stream>>>(x, Wq, bq, tlin);
  topk_attn_k<<<73, 256, 0, stream>>>(tlin, dout);
}

// Round 2
// 320.637 us; speedup vs baseline: 1.0461x; 1.0461x over previous
//
#include <hip/hip_runtime.h>
#include <stdint.h>

typedef __bf16 bf16x8 __attribute__((ext_vector_type(8)));
typedef float f32x4 __attribute__((ext_vector_type(4)));
typedef int i32x4 __attribute__((ext_vector_type(4)));
typedef unsigned short u16;

#define DEVI static __device__ __forceinline__

// f32 -> bf16 (RNE)
DEVI u16 bfu(float f){
  unsigned u = __builtin_bit_cast(unsigned, f);
  unsigned r = u + 0x7fffu + ((u >> 16) & 1u);
  return (u16)(r >> 16);
}
DEVI unsigned packbf(float a, float b){
  return (unsigned)bfu(a) | ((unsigned)bfu(b) << 16);
}

// async global->LDS, 16B per lane. LDS dest is wave-uniform base + lane*16.
DEVI void gload16(const void* g, void* s){
  __builtin_amdgcn_global_load_lds(
      (const __attribute__((address_space(1))) unsigned int*)g,
      (__attribute__((address_space(3))) unsigned int*)s, 16, 0, 0);
}

DEVI float blockReduceMax(float v, float* sred){
  for (int off = 32; off; off >>= 1) v = fmaxf(v, __shfl_xor(v, off));
  int w = threadIdx.x >> 6;
  if ((threadIdx.x & 63) == 0) sred[w] = v;
  __syncthreads();
  float r = fmaxf(fmaxf(sred[0], sred[1]), fmaxf(sred[2], sred[3]));
  __syncthreads();
  return r;
}

// ---------------- quantize kernels ----------------
__global__ void quant_rows(const float* __restrict__ in, int8_t* __restrict__ qo,
                           u16* __restrict__ bo, float* __restrict__ so){
  __shared__ float sred[4];
  const int row = blockIdx.x, t = threadIdx.x;
  const float4 v = *(const float4*)(in + (size_t)row * 1024 + t * 4);
  float am = fmaxf(fmaxf(fabsf(v.x), fabsf(v.y)), fmaxf(fabsf(v.z), fabsf(v.w)));
  am = blockReduceMax(am, sred);
  const float s = fmaxf(am, 1e-5f) / 127.0f;
  if (t == 0) so[row] = s;
  char4 q;
  q.x = (int8_t)(int)fminf(fmaxf(rintf(v.x / s), -128.f), 127.f);
  q.y = (int8_t)(int)fminf(fmaxf(rintf(v.y / s), -128.f), 127.f);
  q.z = (int8_t)(int)fminf(fmaxf(rintf(v.z / s), -128.f), 127.f);
  q.w = (int8_t)(int)fminf(fmaxf(rintf(v.w / s), -128.f), 127.f);
  *(char4*)(qo + (size_t)row * 1024 + t * 4) = q;
  ushort4 h; h.x = bfu(v.x); h.y = bfu(v.y); h.z = bfu(v.z); h.w = bfu(v.w);
  *(ushort4*)(bo + (size_t)row * 1024 + t * 4) = h;
}

__global__ void quant_b(const float* __restrict__ b, float* __restrict__ qb){
  __shared__ float sred[4];
  const int t = threadIdx.x;
  float am = 0.f;
  for (int i = t; i < 3072; i += 256) am = fmaxf(am, fabsf(b[i]));
  am = blockReduceMax(am, sred);
  const float s = fmaxf(am, 1e-5f) / 127.0f;
  for (int i = t; i < 3072; i += 256){
    float q = fminf(fmaxf(rintf(b[i] / s), -128.f), 127.f);
    qb[i] = q * s;
  }
}

__global__ void f32_to_bf16(const float* __restrict__ in, u16* __restrict__ out){
  const int i = (blockIdx.x * 256 + threadIdx.x) * 4;
  float4 v = *(const float4*)(in + i);
  ushort4 h; h.x = bfu(v.x); h.y = bfu(v.y); h.z = bfu(v.z); h.w = bfu(v.w);
  *(ushort4*)(out + i) = h;
}

// ---------------- int8 GEMM: q_lin = sx*sw*(ix.iw^T) + qb ----------------
__global__ __launch_bounds__(256) void gemm_i8(const int8_t* __restrict__ A, const int8_t* __restrict__ Bm,
    const float* __restrict__ sx, const float* __restrict__ sw, const float* __restrict__ qb,
    float* __restrict__ out){
  __shared__ int8_t As[128 * 64];
  __shared__ int8_t Bs[128 * 64];
  const int t = threadIdx.x, l = t & 63, w = t >> 6;
  const int m0 = blockIdx.y * 128, n0 = blockIdx.x * 128;
  const int wm = (w >> 1) * 64, wn = (w & 1) * 64, lr = l & 15, lg = l >> 4;
  i32x4 acc[4][4];
  i32x4 z = {0, 0, 0, 0};
  for (int i = 0; i < 4; i++) for (int j = 0; j < 4; j++) acc[i][j] = z;
  for (int kt = 0; kt < 16; kt++){
    __syncthreads();
    for (int it = 0; it < 2; it++){
      int c = w * 2 + it;                 // chunk 0..7
      int idx = c * 64 + l;               // 0..511
      int r = idx >> 2, boff = (idx & 3) * 16;
      gload16(A  + (size_t)(m0 + r) * 1024 + kt * 64 + boff, &As[c * 1024]);
      gload16(Bm + (size_t)(n0 + r) * 1024 + kt * 64 + boff, &Bs[c * 1024]);
    }
    __syncthreads();
    i32x4 a[4], b[4];
    for (int i = 0; i < 4; i++) a[i] = *(const i32x4*)(&As[(wm + i * 16 + lr) * 64 + lg * 16]);
    for (int j = 0; j < 4; j++) b[j] = *(const i32x4*)(&Bs[(wn + j * 16 + lr) * 64 + lg * 16]);
    for (int i = 0; i < 4; i++)
      for (int j = 0; j < 4; j++)
        acc[i][j] = __builtin_amdgcn_mfma_i32_16x16x64_i8(a[i], b[j], acc[i][j], 0, 0, 0);
  }
  for (int i = 0; i < 4; i++){
    int row = m0 + wm + i * 16 + lg * 4;
    for (int j = 0; j < 4; j++){
      int col = n0 + wn + j * 16 + lr;
      float swc = sw[col], qbc = qb[col];
      for (int r = 0; r < 4; r++)
        out[(size_t)(row + r) * 3072 + col] = (float)acc[i][j][r] * sx[row + r] * swc + qbc;
    }
  }
}

// ---------------- q_lin row quantize -> s_ql, iq, ik ----------------
__global__ void qlin_quant(const float* __restrict__ qlin, float* __restrict__ s_ql,
                           int8_t* __restrict__ iq, int8_t* __restrict__ ik){
  __shared__ float sred[4];
  const int row = blockIdx.x, t = threadIdx.x;
  const float* rp = qlin + (size_t)row * 3072;
  float am = 0.f;
  for (int i = 0; i < 3; i++){
    float4 v = *(const float4*)(rp + t * 4 + i * 1024);
    am = fmaxf(am, fmaxf(fmaxf(fabsf(v.x), fabsf(v.y)), fmaxf(fabsf(v.z), fabsf(v.w))));
  }
  am = blockReduceMax(am, sred);
  const float s = fmaxf(am, 1e-5f) / 127.0f;
  if (t == 0) s_ql[row] = s;
  const int b_ = row >> 10, n = row & 1023;
  const int o0 = t * 8;
  int8_t* dst = (o0 < 1024) ? iq : ik;
  const int oo = o0 & 1023, h = oo >> 6, d = oo & 63;
  const size_t base = (((size_t)(b_ * 16 + h) * 1024 + n) * 64 + d);
  union { int8_t c[8]; unsigned long long u; } pk;
  for (int j = 0; j < 8; j++)
    pk.c[j] = (int8_t)(int)fminf(fmaxf(rintf(rp[o0 + j] / s), -128.f), 127.f);
  *(unsigned long long*)(dst + base) = pk.u;
}

// ---------------- bf16 GEMM (MODE 0: QKV scatter+bias, MODE 1: proj f32 out) ----------------
template<int MODE>
__global__ __launch_bounds__(256) void gemm_bf16(const u16* __restrict__ A, const u16* __restrict__ Bm,
    const float* __restrict__ bias, void* __restrict__ outp, int K, int N){
  __shared__ u16 As[128 * 32];
  __shared__ u16 Bs[128 * 32];
  const int t = threadIdx.x, l = t & 63, w = t >> 6;
  const int m0 = blockIdx.y * 128, n0 = blockIdx.x * 128;
  const int wm = (w >> 1) * 64, wn = (w & 1) * 64, lr = l & 15, lg = l >> 4;
  f32x4 acc[4][4];
  f32x4 z = {0.f, 0.f, 0.f, 0.f};
  for (int i = 0; i < 4; i++) for (int j = 0; j < 4; j++) acc[i][j] = z;
  const int nkt = K >> 5;
  for (int kt = 0; kt < nkt; kt++){
    __syncthreads();
    for (int it = 0; it < 2; it++){
      int c = w * 2 + it;
      int idx = c * 64 + l;
      int r = idx >> 2, off = (idx & 3) * 8;
      gload16(A  + (size_t)(m0 + r) * K + kt * 32 + off, &As[c * 512]);
      gload16(Bm + (size_t)(n0 + r) * K + kt * 32 + off, &Bs[c * 512]);
    }
    __syncthreads();
    bf16x8 a[4], b[4];
    for (int i = 0; i < 4; i++) a[i] = *(const bf16x8*)(&As[(wm + i * 16 + lr) * 32 + lg * 8]);
    for (int j = 0; j < 4; j++) b[j] = *(const bf16x8*)(&Bs[(wn + j * 16 + lr) * 32 + lg * 8]);
    for (int i = 0; i < 4; i++)
      for (int j = 0; j < 4; j++)
        acc[i][j] = __builtin_amdgcn_mfma_f32_16x16x32_bf16(a[i], b[j], acc[i][j], 0, 0, 0);
  }
  for (int i = 0; i < 4; i++){
    int row = m0 + wm + i * 16 + lg * 4;
    for (int j = 0; j < 4; j++){
      int col = n0 + wn + j * 16 + lr;
      float bc = bias[col];
      for (int r = 0; r < 4; r++){
        float v = acc[i][j][r] + bc;
        if (MODE == 0){
          int s = col >> 10, h = (col >> 6) & 15, d = col & 63;
          int b_ = (row + r) >> 10, n = (row + r) & 1023;
          ((u16*)outp)[(((size_t)(s * 64 + b_ * 16 + h)) * 1024 + n) * 64 + d] = bfu(v);
        } else {
          ((float*)outp)[(size_t)(row + r) * N + col] = v;
        }
      }
    }
  }
}

// ---------------- flash attention ----------------
// 4 waves x 16 q-rows; K-frags direct from global (L1/L2-hit); V transposed in
// double-buffered LDS (ONE barrier per 32-KV step); next-V prefetch overlaps compute.
__global__ __launch_bounds__(256) void attn(const u16* __restrict__ qkv, u16* __restrict__ aout){
  __shared__ u16 Vt[2][64][40];       // pad 32->40 (80B rows) to spread read banks
  const int t = threadIdx.x, l = t & 63, w = t >> 6, lr = l & 15, lg = l >> 4;
  const int bz = blockIdx.y, qt = blockIdx.x;
  const int b_ = bz >> 4, h = bz & 15;
  const u16* Q  = qkv + (size_t)bz * 65536;
  const u16* Kg = qkv + (size_t)(64 + bz) * 65536;
  const u16* Vg = qkv + (size_t)(128 + bz) * 65536;
  const int q0 = qt * 64 + w * 16;
  const bf16x8 bq0 = *(const bf16x8*)(Q + (size_t)(q0 + lr) * 64 + lg * 8);
  const bf16x8 bq1 = *(const bf16x8*)(Q + (size_t)(q0 + lr) * 64 + 32 + lg * 8);
  float m = -1e30f, lsum = 0.f;
  f32x4 o[4];
  f32x4 zf = {0.f, 0.f, 0.f, 0.f};
  for (int dt = 0; dt < 4; dt++) o[dt] = zf;
  const int hi = lg & 1, tt = lg >> 1;
  const int srcA = lr + 32 * hi, srcB = srcA + 16;
  const int vr = t >> 3, voff = (t & 7) * 8;     // V stager: row vr (0..31), 8 d-elems
  // prologue: stage V tile 0
  {
    uint4 vv = *(const uint4*)(Vg + (size_t)vr * 64 + voff);
    const u16* pv = (const u16*)&vv;
    for (int j = 0; j < 8; j++) Vt[0][voff + j][vr] = pv[j];
  }
  __syncthreads();
  int cur = 0;
  for (int kv0 = 0; kv0 < 1024; kv0 += 32){
    // K fragments straight from global (same bytes the old LDS staging delivered)
    const bf16x8 ak00 = *(const bf16x8*)(Kg + (size_t)(kv0 + lr) * 64 + lg * 8);
    const bf16x8 ak01 = *(const bf16x8*)(Kg + (size_t)(kv0 + lr) * 64 + 32 + lg * 8);
    const bf16x8 ak10 = *(const bf16x8*)(Kg + (size_t)(kv0 + 16 + lr) * 64 + lg * 8);
    const bf16x8 ak11 = *(const bf16x8*)(Kg + (size_t)(kv0 + 16 + lr) * 64 + 32 + lg * 8);
    // prefetch next V tile into regs (latency hides under softmax+PV)
    const bool more = (kv0 + 32) < 1024;
    uint4 vn = {0, 0, 0, 0};
    if (more) vn = *(const uint4*)(Vg + (size_t)(kv0 + 32 + vr) * 64 + voff);
    f32x4 st[2];
    {
      f32x4 c = zf;
      c = __builtin_amdgcn_mfma_f32_16x16x32_bf16(ak00, bq0, c, 0, 0, 0);
      c = __builtin_amdgcn_mfma_f32_16x16x32_bf16(ak01, bq1, c, 0, 0, 0);
      st[0] = c;
      c = zf;
      c = __builtin_amdgcn_mfma_f32_16x16x32_bf16(ak10, bq0, c, 0, 0, 0);
      c = __builtin_amdgcn_mfma_f32_16x16x32_bf16(ak11, bq1, c, 0, 0, 0);
      st[1] = c;
    }
    float tmax = -1e30f;
    for (int kvt = 0; kvt < 2; kvt++)
      for (int r = 0; r < 4; r++){ st[kvt][r] *= 0.125f; tmax = fmaxf(tmax, st[kvt][r]); }
    tmax = fmaxf(tmax, __shfl_xor(tmax, 16));
    tmax = fmaxf(tmax, __shfl_xor(tmax, 32));
    const float mn = fmaxf(m, tmax);
    const float f = __expf(m - mn);
    m = mn;
    float p[2][4], psum = 0.f;
    for (int kvt = 0; kvt < 2; kvt++)
      for (int r = 0; r < 4; r++){ float e = __expf(st[kvt][r] - mn); p[kvt][r] = e; psum += e; }
    psum += __shfl_xor(psum, 16);
    psum += __shfl_xor(psum, 32);
    lsum = lsum * f + psum;
    for (int dt = 0; dt < 4; dt++) for (int r = 0; r < 4; r++) o[dt][r] *= f;
    // repack P^T (C-layout) -> B-frag layout via shuffles
    int pk00 = (int)packbf(p[0][0], p[0][1]), pk01 = (int)packbf(p[0][2], p[0][3]);
    int pk10 = (int)packbf(p[1][0], p[1][1]), pk11 = (int)packbf(p[1][2], p[1][3]);
    int a0 = __shfl(pk00, srcA), a1 = __shfl(pk10, srcA);
    int b0 = __shfl(pk01, srcA), b1 = __shfl(pk11, srcA);
    int c0 = __shfl(pk00, srcB), c1 = __shfl(pk10, srcB);
    int d0 = __shfl(pk01, srcB), d1 = __shfl(pk11, srcB);
    union { unsigned u[4]; bf16x8 v; } bp;
    bp.u[0] = (unsigned)(tt ? a1 : a0);
    bp.u[1] = (unsigned)(tt ? b1 : b0);
    bp.u[2] = (unsigned)(tt ? c1 : c0);
    bp.u[3] = (unsigned)(tt ? d1 : d0);
    for (int dt = 0; dt < 4; dt++){
      bf16x8 av = *(const bf16x8*)(&Vt[cur][dt * 16 + lr][lg * 8]);
      o[dt] = __builtin_amdgcn_mfma_f32_16x16x32_bf16(av, bp.v, o[dt], 0, 0, 0);
    }
    // stage next V into the other buffer; single barrier closes the iteration
    if (more){
      const u16* pv = (const u16*)&vn;
      for (int j = 0; j < 8; j++) Vt[cur ^ 1][voff + j][vr] = pv[j];
    }
    __syncthreads();
    cur ^= 1;
  }
  const float rn = 1.0f / lsum;
  for (int dt = 0; dt < 4; dt++){
    ushort4 hv;
    hv.x = bfu(o[dt][0] * rn); hv.y = bfu(o[dt][1] * rn);
    hv.z = bfu(o[dt][2] * rn); hv.w = bfu(o[dt][3] * rn);
    *(ushort4*)(aout + ((size_t)(b_ * 1024 + q0 + lr)) * 1024 + h * 64 + dt * 16 + lg * 4) = hv;
  }
}

// ---------------- q_attn: exact int8 scores ----------------
__global__ __launch_bounds__(256) void qattn(const int8_t* __restrict__ iq, const int8_t* __restrict__ ik,
    const float* __restrict__ s_ql, float* __restrict__ outp){
  const int t = threadIdx.x, l = t & 63, w = t >> 6, lr = l & 15, lg = l >> 4;
  const int bz = blockIdx.z, m0 = blockIdx.y * 128, n0 = blockIdx.x * 128;
  const int wm = (w >> 1) * 64, wn = (w & 1) * 64;
  const int b_ = bz >> 4;
  const int8_t* Aq = iq + (size_t)bz * 65536;
  const int8_t* Bk = ik + (size_t)bz * 65536;
  i32x4 a[4], b[4];
  for (int i = 0; i < 4; i++) a[i] = *(const i32x4*)(Aq + (size_t)(m0 + wm + i * 16 + lr) * 64 + lg * 16);
  for (int j = 0; j < 4; j++) b[j] = *(const i32x4*)(Bk + (size_t)(n0 + wn + j * 16 + lr) * 64 + lg * 16);
  float* op = outp + 4194304 + (size_t)bz * 1048576;
  i32x4 z = {0, 0, 0, 0};
  for (int i = 0; i < 4; i++){
    int row = m0 + wm + i * 16 + lg * 4;
    for (int j = 0; j < 4; j++){
      i32x4 acc = __builtin_amdgcn_mfma_i32_16x16x64_i8(a[i], b[j], z, 0, 0, 0);
      int col = n0 + wn + j * 16 + lr;
      float sc = s_ql[b_ * 1024 + col] * 0.125f;
      for (int r = 0; r < 4; r++)
        op[(size_t)(row + r) * 1024 + col] = (float)acc[r] * s_ql[b_ * 1024 + row + r] * sc;
    }
  }
}

// ---------------- topk path (tiny, f32 exact) ----------------
__global__ void topk_lin(const float* __restrict__ x, const float* __restrict__ Wq,
                         const float* __restrict__ bq, float* __restrict__ tlin){
  const int idx = blockIdx.x * 256 + threadIdx.x;
  const int o = idx & 2047, bn = idx >> 11;
  const int b_ = bn / 17, n = bn % 17;
  const float* xr = x + ((size_t)b_ * 1024 + n) * 1024;
  const float* wr = Wq + (size_t)o * 1024;
  float s = 0.f;
  for (int c = 0; c < 257; c++) s += xr[c] * wr[c];
  tlin[idx] = s + bq[o];
}

__global__ void topk_attn_k(const float* __restrict__ tlin, float* __restrict__ outp){
  const int idx = blockIdx.x * 256 + threadIdx.x;
  if (idx >= 4 * 16 * 17 * 17) return;
  const int mm = idx % 17; int rest = idx / 17;
  const int nn = rest % 17; rest /= 17;
  const int h = rest % 16; const int b_ = rest / 16;
  const float* tq = tlin + ((size_t)(b_ * 17 + nn)) * 2048 + h * 64;
  const float* tk = tlin + ((size_t)(b_ * 17 + mm)) * 2048 + 1024 + h * 64;
  float s = 0.f;
  for (int d = 0; d < 64; d++) s += tq[d] * tk[d];
  outp[71303168 + idx] = s * 0.125f;
}

// ---------------- launcher ----------------
extern "C" void kernel_launch(void* const* d_in, const int* in_sizes, int n_in,
                              void* d_out, int out_size, void* d_ws, size_t ws_size,
                              hipStream_t stream){
  const float* x  = (const float*)d_in[0];
  const float* Wq = (const float*)d_in[1];
  const float* bq = (const float*)d_in[2];
  const float* Wp = (const float*)d_in[3];
  const float* bp = (const float*)d_in[4];
  char* ws = (char*)d_ws;
  size_t off = 0;
  auto alloc = [&](size_t bytes) -> void* {
    void* p = ws + off; off += (bytes + 255) & ~(size_t)255; return p;
  };
  float*  qlin = (float*) alloc(4096ull * 3072 * 4);
  int8_t* ix   = (int8_t*)alloc(4096ull * 1024);
  int8_t* iw   = (int8_t*)alloc(3072ull * 1024);
  int8_t* iq   = (int8_t*)alloc(64ull * 1024 * 64);
  int8_t* ik   = (int8_t*)alloc(64ull * 1024 * 64);
  u16*    xb   = (u16*)   alloc(4096ull * 1024 * 2);
  u16*    Wb   = (u16*)   alloc(3072ull * 1024 * 2);
  u16*    qkv  = (u16*)   alloc(3ull * 64 * 1024 * 64 * 2);
  u16*    aout = (u16*)   alloc(4096ull * 1024 * 2);
  u16*    Wpb  = (u16*)   alloc(1024ull * 1024 * 2);
  float*  tlin = (float*) alloc(4ull * 17 * 2048 * 4);
  float*  sx   = (float*) alloc(4096 * 4);
  float*  sw   = (float*) alloc(3072 * 4);
  float*  qbv  = (float*) alloc(3072 * 4);
  float*  sql  = (float*) alloc(4096 * 4);
  float*  dout = (float*)d_out;

  quant_rows<<<4096, 256, 0, stream>>>(x, ix, xb, sx);
  quant_rows<<<3072, 256, 0, stream>>>(Wq, iw, Wb, sw);
  quant_b<<<1, 256, 0, stream>>>(bq, qbv);
  f32_to_bf16<<<1024, 256, 0, stream>>>(Wp, Wpb);
  gemm_i8<<<dim3(24, 32), 256, 0, stream>>>(ix, iw, sx, sw, qbv, qlin);
  qlin_quant<<<4096, 256, 0, stream>>>(qlin, sql, iq, ik);
  gemm_bf16<0><<<dim3(24, 32), 256, 0, stream>>>(xb, Wb, bq, qkv, 1024, 3072);
  attn<<<dim3(16, 64), 256, 0, stream>>>(qkv, aout);
  gemm_bf16<1><<<dim3(8, 32), 256, 0, stream>>>(aout, Wpb, bp, dout, 1024, 1024);
  qattn<<<dim3(8, 8, 64), 256, 0, stream>>>(iq, ik, sql, dout);
  topk_lin<<<544, 256, 0, stream>>>(x, Wq, bq, tlin);
  topk_attn_k<<<73, 256, 0, stream>>>(tlin, dout);
}

// Round 3
// 278.730 us; speedup vs baseline: 1.2034x; 1.1503x over previous
//
#include <hip/hip_runtime.h>
#include <stdint.h>

typedef __bf16 bf16x8 __attribute__((ext_vector_type(8)));
typedef float f32x4 __attribute__((ext_vector_type(4)));
typedef int i32x4 __attribute__((ext_vector_type(4)));
typedef unsigned short u16;

#define DEVI static __device__ __forceinline__

// f32 -> bf16 (RNE)
DEVI u16 bfu(float f){
  unsigned u = __builtin_bit_cast(unsigned, f);
  unsigned r = u + 0x7fffu + ((u >> 16) & 1u);
  return (u16)(r >> 16);
}
DEVI unsigned packbf(float a, float b){
  return (unsigned)bfu(a) | ((unsigned)bfu(b) << 16);
}

// async global->LDS, 16B/lane; LDS dest = wave-uniform base + lane*16
DEVI void gload16(const void* g, void* s){
  __builtin_amdgcn_global_load_lds(
      (const __attribute__((address_space(1))) unsigned int*)g,
      (__attribute__((address_space(3))) unsigned int*)s, 16, 0, 0);
}

DEVI float blockReduceMax(float v, float* sred){
  for (int off = 32; off; off >>= 1) v = fmaxf(v, __shfl_xor(v, off));
  int w = threadIdx.x >> 6;
  if ((threadIdx.x & 63) == 0) sred[w] = v;
  __syncthreads();
  float r = fmaxf(fmaxf(sred[0], sred[1]), fmaxf(sred[2], sred[3]));
  __syncthreads();
  return r;
}

// ---------------- bodies ----------------
DEVI void quant_row_body(const float* __restrict__ in, int8_t* __restrict__ qo,
                         u16* __restrict__ bo, float* __restrict__ so, int row, float* sred){
  const int t = threadIdx.x;
  const float4 v = *(const float4*)(in + (size_t)row * 1024 + t * 4);
  float am = fmaxf(fmaxf(fabsf(v.x), fabsf(v.y)), fmaxf(fabsf(v.z), fabsf(v.w)));
  am = blockReduceMax(am, sred);
  const float s = fmaxf(am, 1e-5f) / 127.0f;
  if (t == 0) so[row] = s;
  char4 q;
  q.x = (int8_t)(int)fminf(fmaxf(rintf(v.x / s), -128.f), 127.f);
  q.y = (int8_t)(int)fminf(fmaxf(rintf(v.y / s), -128.f), 127.f);
  q.z = (int8_t)(int)fminf(fmaxf(rintf(v.z / s), -128.f), 127.f);
  q.w = (int8_t)(int)fminf(fmaxf(rintf(v.w / s), -128.f), 127.f);
  *(char4*)(qo + (size_t)row * 1024 + t * 4) = q;
  ushort4 h; h.x = bfu(v.x); h.y = bfu(v.y); h.z = bfu(v.z); h.w = bfu(v.w);
  *(ushort4*)(bo + (size_t)row * 1024 + t * 4) = h;
}

DEVI void quant_b_body(const float* __restrict__ b, float* __restrict__ qb, float* sred){
  const int t = threadIdx.x;
  float am = 0.f;
  for (int i = t; i < 3072; i += 256) am = fmaxf(am, fabsf(b[i]));
  am = blockReduceMax(am, sred);
  const float s = fmaxf(am, 1e-5f) / 127.0f;
  for (int i = t; i < 3072; i += 256){
    float q = fminf(fmaxf(rintf(b[i] / s), -128.f), 127.f);
    qb[i] = q * s;
  }
}

DEVI void topk_lin_body(int idx, const float* __restrict__ x, const float* __restrict__ Wq,
                        const float* __restrict__ bq, float* __restrict__ tlin){
  const int o = idx & 2047, bn = idx >> 11;
  const int b_ = bn / 17, n = bn % 17;
  const float* xr = x + ((size_t)b_ * 1024 + n) * 1024;
  const float* wr = Wq + (size_t)o * 1024;
  const float4* x4 = (const float4*)xr;
  const float4* w4 = (const float4*)wr;
  float s = 0.f;
  for (int c = 0; c < 64; c++){
    float4 a = x4[c], b = w4[c];
    s += a.x * b.x + a.y * b.y + a.z * b.z + a.w * b.w;
  }
  s += xr[256] * wr[256];
  tlin[idx] = s + bq[o];
}

DEVI void gemm_i8_body(char* smem, int bid, const int8_t* __restrict__ A, const int8_t* __restrict__ Bm,
    const float* __restrict__ sx, const float* __restrict__ sw, const float* __restrict__ qb,
    float* __restrict__ out){
  int8_t* As = (int8_t*)smem;
  int8_t* Bs = (int8_t*)(smem + 8192);
  const int t = threadIdx.x, l = t & 63, w = t >> 6;
  const int m0 = (bid / 24) * 128, n0 = (bid % 24) * 128;
  const int wm = (w >> 1) * 64, wn = (w & 1) * 64, lr = l & 15, lg = l >> 4;
  i32x4 acc[4][4];
  i32x4 z = {0, 0, 0, 0};
  for (int i = 0; i < 4; i++) for (int j = 0; j < 4; j++) acc[i][j] = z;
  for (int kt = 0; kt < 16; kt++){
    __syncthreads();
    for (int it = 0; it < 2; it++){
      int c = w * 2 + it;
      int idx = c * 64 + l;
      int r = idx >> 2, boff = (idx & 3) * 16;
      gload16(A  + (size_t)(m0 + r) * 1024 + kt * 64 + boff, &As[c * 1024]);
      gload16(Bm + (size_t)(n0 + r) * 1024 + kt * 64 + boff, &Bs[c * 1024]);
    }
    __syncthreads();
    i32x4 a[4], b[4];
    for (int i = 0; i < 4; i++) a[i] = *(const i32x4*)(&As[(wm + i * 16 + lr) * 64 + lg * 16]);
    for (int j = 0; j < 4; j++) b[j] = *(const i32x4*)(&Bs[(wn + j * 16 + lr) * 64 + lg * 16]);
    for (int i = 0; i < 4; i++)
      for (int j = 0; j < 4; j++)
        acc[i][j] = __builtin_amdgcn_mfma_i32_16x16x64_i8(a[i], b[j], acc[i][j], 0, 0, 0);
  }
  for (int i = 0; i < 4; i++){
    int row = m0 + wm + i * 16 + lg * 4;
    for (int j = 0; j < 4; j++){
      int col = n0 + wn + j * 16 + lr;
      float swc = sw[col], qbc = qb[col];
      for (int r = 0; r < 4; r++)
        out[(size_t)(row + r) * 3072 + col] = (float)acc[i][j][r] * sx[row + r] * swc + qbc;
    }
  }
}

template<int MODE>
DEVI void gemm_bf16_body(char* smem, int bid, const u16* __restrict__ A, const u16* __restrict__ Bm,
    const float* __restrict__ bias, void* __restrict__ outp, int K, int N, int nxb){
  u16* As = (u16*)smem;
  u16* Bs = (u16*)(smem + 8192);
  const int t = threadIdx.x, l = t & 63, w = t >> 6;
  const int m0 = (bid / nxb) * 128, n0 = (bid % nxb) * 128;
  const int wm = (w >> 1) * 64, wn = (w & 1) * 64, lr = l & 15, lg = l >> 4;
  f32x4 acc[4][4];
  f32x4 z = {0.f, 0.f, 0.f, 0.f};
  for (int i = 0; i < 4; i++) for (int j = 0; j < 4; j++) acc[i][j] = z;
  const int nkt = K >> 5;
  for (int kt = 0; kt < nkt; kt++){
    __syncthreads();
    for (int it = 0; it < 2; it++){
      int c = w * 2 + it;
      int idx = c * 64 + l;
      int r = idx >> 2, off = (idx & 3) * 8;
      gload16(A  + (size_t)(m0 + r) * K + kt * 32 + off, &As[c * 512]);
      gload16(Bm + (size_t)(n0 + r) * K + kt * 32 + off, &Bs[c * 512]);
    }
    __syncthreads();
    bf16x8 a[4], b[4];
    for (int i = 0; i < 4; i++) a[i] = *(const bf16x8*)(&As[(wm + i * 16 + lr) * 32 + lg * 8]);
    for (int j = 0; j < 4; j++) b[j] = *(const bf16x8*)(&Bs[(wn + j * 16 + lr) * 32 + lg * 8]);
    for (int i = 0; i < 4; i++)
      for (int j = 0; j < 4; j++)
        acc[i][j] = __builtin_amdgcn_mfma_f32_16x16x32_bf16(a[i], b[j], acc[i][j], 0, 0, 0);
  }
  for (int i = 0; i < 4; i++){
    int row = m0 + wm + i * 16 + lg * 4;
    for (int j = 0; j < 4; j++){
      int col = n0 + wn + j * 16 + lr;
      float bc = bias[col];
      for (int r = 0; r < 4; r++){
        float v = acc[i][j][r] + bc;
        if (MODE == 0){
          int s = col >> 10, h = (col >> 6) & 15, d = col & 63;
          int b_ = (row + r) >> 10, n = (row + r) & 1023;
          ((u16*)outp)[(((size_t)(s * 64 + b_ * 16 + h)) * 1024 + n) * 64 + d] = bfu(v);
        } else {
          ((float*)outp)[(size_t)(row + r) * N + col] = v;
        }
      }
    }
  }
}

DEVI void topk_attn_body(int b2, const float* __restrict__ tlin, float* __restrict__ outp){
  const int idx = b2 * 256 + threadIdx.x;
  if (idx >= 4 * 16 * 17 * 17) return;
  const int mm = idx % 17; int rest = idx / 17;
  const int nn = rest % 17; rest /= 17;
  const int h = rest % 16; const int b_ = rest / 16;
  const float* tq = tlin + ((size_t)(b_ * 17 + nn)) * 2048 + h * 64;
  const float* tk = tlin + ((size_t)(b_ * 17 + mm)) * 2048 + 1024 + h * 64;
  float s = 0.f;
  for (int d = 0; d < 64; d++) s += tq[d] * tk[d];
  outp[71303168 + idx] = s * 0.125f;
}

DEVI void qlin_quant_body(float* sred, int row, const float* __restrict__ qlin,
                          float* __restrict__ s_ql, int8_t* __restrict__ iq, int8_t* __restrict__ ik){
  const int t = threadIdx.x;
  const float* rp = qlin + (size_t)row * 3072;
  float am = 0.f;
  for (int i = 0; i < 3; i++){
    float4 v = *(const float4*)(rp + t * 4 + i * 1024);
    am = fmaxf(am, fmaxf(fmaxf(fabsf(v.x), fabsf(v.y)), fmaxf(fabsf(v.z), fabsf(v.w))));
  }
  am = blockReduceMax(am, sred);
  const float s = fmaxf(am, 1e-5f) / 127.0f;
  if (t == 0) s_ql[row] = s;
  const int b_ = row >> 10, n = row & 1023;
  const int o0 = t * 8;
  int8_t* dst = (o0 < 1024) ? iq : ik;
  const int oo = o0 & 1023, h = oo >> 6, d = oo & 63;
  const size_t base = (((size_t)(b_ * 16 + h) * 1024 + n) * 64 + d);
  union { int8_t c[8]; unsigned long long u; } pk;
  for (int j = 0; j < 8; j++)
    pk.c[j] = (int8_t)(int)fminf(fmaxf(rintf(rp[o0 + j] / s), -128.f), 127.f);
  *(unsigned long long*)(dst + base) = pk.u;
}

DEVI void attn_body(u16* vt, int qt, int bz, const u16* __restrict__ qkv, u16* __restrict__ aout){
  const int t = threadIdx.x, l = t & 63, w = t >> 6, lr = l & 15, lg = l >> 4;
  const int b_ = bz >> 4, h = bz & 15;
  const u16* Q  = qkv + (size_t)bz * 65536;
  const u16* Kg = qkv + (size_t)(64 + bz) * 65536;
  const u16* Vg = qkv + (size_t)(128 + bz) * 65536;
  const int q0 = qt * 64 + w * 16;
  const bf16x8 bq0 = *(const bf16x8*)(Q + (size_t)(q0 + lr) * 64 + lg * 8);
  const bf16x8 bq1 = *(const bf16x8*)(Q + (size_t)(q0 + lr) * 64 + 32 + lg * 8);
  float m = -1e30f, lsum = 0.f;
  f32x4 o[4];
  f32x4 zf = {0.f, 0.f, 0.f, 0.f};
  for (int dt = 0; dt < 4; dt++) o[dt] = zf;
  const int hi = lg & 1, tt = lg >> 1;
  const int srcA = lr + 32 * hi, srcB = srcA + 16;
  const int vr = t >> 3, voff = (t & 7) * 8;
  {
    uint4 vv = *(const uint4*)(Vg + (size_t)vr * 64 + voff);
    const u16* pv = (const u16*)&vv;
    for (int j = 0; j < 8; j++) vt[(0 * 64 + voff + j) * 40 + vr] = pv[j];
  }
  __syncthreads();
  int cur = 0;
  for (int kv0 = 0; kv0 < 1024; kv0 += 32){
    const bf16x8 ak00 = *(const bf16x8*)(Kg + (size_t)(kv0 + lr) * 64 + lg * 8);
    const bf16x8 ak01 = *(const bf16x8*)(Kg + (size_t)(kv0 + lr) * 64 + 32 + lg * 8);
    const bf16x8 ak10 = *(const bf16x8*)(Kg + (size_t)(kv0 + 16 + lr) * 64 + lg * 8);
    const bf16x8 ak11 = *(const bf16x8*)(Kg + (size_t)(kv0 + 16 + lr) * 64 + 32 + lg * 8);
    const bool more = (kv0 + 32) < 1024;
    uint4 vn = {0, 0, 0, 0};
    if (more) vn = *(const uint4*)(Vg + (size_t)(kv0 + 32 + vr) * 64 + voff);
    f32x4 st[2];
    {
      f32x4 c = zf;
      c = __builtin_amdgcn_mfma_f32_16x16x32_bf16(ak00, bq0, c, 0, 0, 0);
      c = __builtin_amdgcn_mfma_f32_16x16x32_bf16(ak01, bq1, c, 0, 0, 0);
      st[0] = c;
      c = zf;
      c = __builtin_amdgcn_mfma_f32_16x16x32_bf16(ak10, bq0, c, 0, 0, 0);
      c = __builtin_amdgcn_mfma_f32_16x16x32_bf16(ak11, bq1, c, 0, 0, 0);
      st[1] = c;
    }
    float tmax = -1e30f;
    for (int kvt = 0; kvt < 2; kvt++)
      for (int r = 0; r < 4; r++){ st[kvt][r] *= 0.125f; tmax = fmaxf(tmax, st[kvt][r]); }
    tmax = fmaxf(tmax, __shfl_xor(tmax, 16));
    tmax = fmaxf(tmax, __shfl_xor(tmax, 32));
    const float mn = fmaxf(m, tmax);
    const float f = __expf(m - mn);
    m = mn;
    float p[2][4], psum = 0.f;
    for (int kvt = 0; kvt < 2; kvt++)
      for (int r = 0; r < 4; r++){ float e = __expf(st[kvt][r] - mn); p[kvt][r] = e; psum += e; }
    psum += __shfl_xor(psum, 16);
    psum += __shfl_xor(psum, 32);
    lsum = lsum * f + psum;
    for (int dt = 0; dt < 4; dt++) for (int r = 0; r < 4; r++) o[dt][r] *= f;
    int pk00 = (int)packbf(p[0][0], p[0][1]), pk01 = (int)packbf(p[0][2], p[0][3]);
    int pk10 = (int)packbf(p[1][0], p[1][1]), pk11 = (int)packbf(p[1][2], p[1][3]);
    int a0 = __shfl(pk00, srcA), a1 = __shfl(pk10, srcA);
    int b0 = __shfl(pk01, srcA), b1 = __shfl(pk11, srcA);
    int c0 = __shfl(pk00, srcB), c1 = __shfl(pk10, srcB);
    int d0 = __shfl(pk01, srcB), d1 = __shfl(pk11, srcB);
    union { unsigned u[4]; bf16x8 v; } bp;
    bp.u[0] = (unsigned)(tt ? a1 : a0);
    bp.u[1] = (unsigned)(tt ? b1 : b0);
    bp.u[2] = (unsigned)(tt ? c1 : c0);
    bp.u[3] = (unsigned)(tt ? d1 : d0);
    for (int dt = 0; dt < 4; dt++){
      bf16x8 av = *(const bf16x8*)(&vt[(cur * 64 + dt * 16 + lr) * 40 + lg * 8]);
      o[dt] = __builtin_amdgcn_mfma_f32_16x16x32_bf16(av, bp.v, o[dt], 0, 0, 0);
    }
    if (more){
      const u16* pv = (const u16*)&vn;
      for (int j = 0; j < 8; j++) vt[((cur ^ 1) * 64 + voff + j) * 40 + vr] = pv[j];
    }
    __syncthreads();
    cur ^= 1;
  }
  const float rn = 1.0f / lsum;
  for (int dt = 0; dt < 4; dt++){
    ushort4 hv;
    hv.x = bfu(o[dt][0] * rn); hv.y = bfu(o[dt][1] * rn);
    hv.z = bfu(o[dt][2] * rn); hv.w = bfu(o[dt][3] * rn);
    *(ushort4*)(aout + ((size_t)(b_ * 1024 + q0 + lr)) * 1024 + h * 64 + dt * 16 + lg * 4) = hv;
  }
}

DEVI void qattn_body(int b2, const int8_t* __restrict__ iq, const int8_t* __restrict__ ik,
    const float* __restrict__ s_ql, float* __restrict__ outp){
  const int t = threadIdx.x, l = t & 63, w = t >> 6, lr = l & 15, lg = l >> 4;
  const int n0 = (b2 & 7) * 128, m0 = ((b2 >> 3) & 7) * 128, bz = b2 >> 6;
  const int wm = (w >> 1) * 64, wn = (w & 1) * 64;
  const int b_ = bz >> 4;
  const int8_t* Aq = iq + (size_t)bz * 65536;
  const int8_t* Bk = ik + (size_t)bz * 65536;
  i32x4 a[4], b[4];
  for (int i = 0; i < 4; i++) a[i] = *(const i32x4*)(Aq + (size_t)(m0 + wm + i * 16 + lr) * 64 + lg * 16);
  for (int j = 0; j < 4; j++) b[j] = *(const i32x4*)(Bk + (size_t)(n0 + wn + j * 16 + lr) * 64 + lg * 16);
  float* op = outp + 4194304 + (size_t)bz * 1048576;
  i32x4 z = {0, 0, 0, 0};
  for (int i = 0; i < 4; i++){
    int row = m0 + wm + i * 16 + lg * 4;
    for (int j = 0; j < 4; j++){
      i32x4 acc = __builtin_amdgcn_mfma_i32_16x16x64_i8(a[i], b[j], z, 0, 0, 0);
      int col = n0 + wn + j * 16 + lr;
      float sc = s_ql[b_ * 1024 + col] * 0.125f;
      for (int r = 0; r < 4; r++)
        op[(size_t)(row + r) * 1024 + col] = (float)acc[r] * s_ql[b_ * 1024 + row + r] * sc;
    }
  }
}

// ---------------- stage kernels ----------------
__global__ __launch_bounds__(256) void stageA(
    const float* __restrict__ x, const float* __restrict__ Wq, const float* __restrict__ bq,
    const float* __restrict__ Wp,
    int8_t* __restrict__ ix, u16* __restrict__ xb, float* __restrict__ sx,
    int8_t* __restrict__ iw, u16* __restrict__ wb, float* __restrict__ sw,
    float* __restrict__ qbv, u16* __restrict__ Wpb, float* __restrict__ tlin){
  __shared__ float sred[4];
  const int bid = blockIdx.x, t = threadIdx.x;
  if (bid < 4096){
    quant_row_body(x, ix, xb, sx, bid, sred);
  } else if (bid < 7168){
    quant_row_body(Wq, iw, wb, sw, bid - 4096, sred);
  } else if (bid == 7168){
    quant_b_body(bq, qbv, sred);
  } else if (bid < 7169 + 1024){
    const int i = ((bid - 7169) * 256 + t) * 4;
    float4 v = *(const float4*)(Wp + i);
    ushort4 h; h.x = bfu(v.x); h.y = bfu(v.y); h.z = bfu(v.z); h.w = bfu(v.w);
    *(ushort4*)(Wpb + i) = h;
  } else {
    topk_lin_body((bid - 8193) * 256 + t, x, Wq, bq, tlin);
  }
}

__global__ __launch_bounds__(256) void stageB(
    const int8_t* __restrict__ ix, const int8_t* __restrict__ iw, const float* __restrict__ sx,
    const float* __restrict__ sw, const float* __restrict__ qbv, float* __restrict__ qlin,
    const u16* __restrict__ xb, const u16* __restrict__ wb, const float* __restrict__ bq,
    u16* __restrict__ qkv, const float* __restrict__ tlin, float* __restrict__ dout){
  __shared__ __align__(16) char smem[16384];
  const int bid = blockIdx.x;
  if (bid < 768) gemm_i8_body(smem, bid, ix, iw, sx, sw, qbv, qlin);
  else if (bid < 1536) gemm_bf16_body<0>(smem, bid - 768, xb, wb, bq, qkv, 1024, 3072, 24);
  else topk_attn_body(bid - 1536, tlin, dout);
}

__global__ __launch_bounds__(256) void stageC(
    const u16* __restrict__ qkv, u16* __restrict__ aout,
    const float* __restrict__ qlin, float* __restrict__ sql,
    int8_t* __restrict__ iq, int8_t* __restrict__ ik){
  __shared__ __align__(16) char smem[10240];
  const int bid = blockIdx.x;
  if (bid < 1024) attn_body((u16*)smem, bid & 15, bid >> 4, qkv, aout);
  else qlin_quant_body((float*)smem, bid - 1024, qlin, sql, iq, ik);
}

__global__ __launch_bounds__(256) void stageD(
    const u16* __restrict__ aout, const u16* __restrict__ Wpb, const float* __restrict__ bp,
    float* __restrict__ dout,
    const int8_t* __restrict__ iq, const int8_t* __restrict__ ik, const float* __restrict__ sql){
  __shared__ __align__(16) char smem[16384];
  const int bid = blockIdx.x;
  if (bid < 256) gemm_bf16_body<1>(smem, bid, aout, Wpb, bp, dout, 1024, 1024, 8);
  else qattn_body(bid - 256, iq, ik, sql, dout);
}

// ---------------- launcher ----------------
extern "C" void kernel_launch(void* const* d_in, const int* in_sizes, int n_in,
                              void* d_out, int out_size, void* d_ws, size_t ws_size,
                              hipStream_t stream){
  const float* x  = (const float*)d_in[0];
  const float* Wq = (const float*)d_in[1];
  const float* bq = (const float*)d_in[2];
  const float* Wp = (const float*)d_in[3];
  const float* bp = (const float*)d_in[4];
  char* ws = (char*)d_ws;
  size_t off = 0;
  auto alloc = [&](size_t bytes) -> void* {
    void* p = ws + off; off += (bytes + 255) & ~(size_t)255; return p;
  };
  float*  qlin = (float*) alloc(4096ull * 3072 * 4);
  int8_t* ix   = (int8_t*)alloc(4096ull * 1024);
  int8_t* iw   = (int8_t*)alloc(3072ull * 1024);
  int8_t* iq   = (int8_t*)alloc(64ull * 1024 * 64);
  int8_t* ik   = (int8_t*)alloc(64ull * 1024 * 64);
  u16*    xb   = (u16*)   alloc(4096ull * 1024 * 2);
  u16*    Wb   = (u16*)   alloc(3072ull * 1024 * 2);
  u16*    qkv  = (u16*)   alloc(3ull * 64 * 1024 * 64 * 2);
  u16*    aout = (u16*)   alloc(4096ull * 1024 * 2);
  u16*    Wpb  = (u16*)   alloc(1024ull * 1024 * 2);
  float*  tlin = (float*) alloc(4ull * 17 * 2048 * 4);
  float*  sx   = (float*) alloc(4096 * 4);
  float*  sw   = (float*) alloc(3072 * 4);
  float*  qbv  = (float*) alloc(3072 * 4);
  float*  sql  = (float*) alloc(4096 * 4);
  float*  dout = (float*)d_out;

  stageA<<<8737, 256, 0, stream>>>(x, Wq, bq, Wp, ix, xb, sx, iw, Wb, sw, qbv, Wpb, tlin);
  stageB<<<1609, 256, 0, stream>>>(ix, iw, sx, sw, qbv, qlin, xb, Wb, bq, qkv, tlin, dout);
  stageC<<<5120, 256, 0, stream>>>(qkv, aout, qlin, sql, iq, ik);
  stageD<<<4352, 256, 0, stream>>>(aout, Wpb, bp, dout, iq, ik, sql);
}